// Round 5
// baseline (329.193 us; speedup 1.0000x reference)
//
#include <hip/hip_runtime.h>
#include <math.h>

#define N_TOK 16384
#define DM    2048
#define NE    64
#define TOPK  4

#define OFF_TI  0
#define OFF_TS  (N_TOK * TOPK)
#define OFF_SC  (2 * N_TOK * TOPK)
#define OFF_AUX (2 * N_TOK * TOPK + N_TOK * NE)

// ---------------- MFMA path ----------------
#define MTPB  16             // tokens per block -> grid 1024 = 4 blocks/CU
#define RW    256            // dims per staged round (4 waves x 64)
#define NRND  (DM / RW)      // 8
#define RSTR  264            // u bf16 plane row stride (528B: bank-balanced b128)
#define PLN   (MTPB * RSTR)  // 4224 bf16 per plane
                             // buffers: [buf][hi PLN][lo PLN], 2 bufs = 33792 B

#define EH_OFF   1024                      // byte offset of Eh_t in ws
#define ET_ELEMS ((size_t)NE * DM)
#define WS_NEED  (EH_OFF + 4 * ET_ELEMS)   // 525,312 B

typedef short s8v __attribute__((ext_vector_type(8)));   // 8 bf16 = 4 VGPR
typedef float f4v __attribute__((ext_vector_type(4)));

__device__ __forceinline__ unsigned short bf16_rne(float x) {
  unsigned int b = __float_as_uint(x);
  b += 0x7FFFu + ((b >> 16) & 1u);
  return (unsigned short)(b >> 16);
}

// E[2048][64] f32 -> Eh_t/El_t[64 e][2048 k] bf16 (split: E = hi + lo + ~2^-18).
__global__ __launch_bounds__(256) void router_prep(
    const float* __restrict__ E, unsigned short* __restrict__ eh,
    unsigned short* __restrict__ el)
{
  __shared__ float t[32][65];
  const int tid = threadIdx.x;
  const int k0  = blockIdx.x * 32;
#pragma unroll
  for (int i = 0; i < 2; ++i) {
    const int fi = i * 256 + tid;
    const int kk = fi >> 4, ee = (fi & 15) * 4;
    const float4 v = *(const float4*)(E + (size_t)(k0 + kk) * NE + ee);
    t[kk][ee] = v.x; t[kk][ee + 1] = v.y; t[kk][ee + 2] = v.z; t[kk][ee + 3] = v.w;
  }
  __syncthreads();
  const int e = tid >> 2, ks = (tid & 3) * 8;
  unsigned int hw[4], lw[4];
#pragma unroll
  for (int p = 0; p < 4; ++p) {
    unsigned short h[2], l[2];
#pragma unroll
    for (int q = 0; q < 2; ++q) {
      const float x = t[ks + p * 2 + q][e];
      h[q] = bf16_rne(x);
      l[q] = bf16_rne(x - __uint_as_float((unsigned)h[q] << 16));
    }
    hw[p] = (unsigned)h[0] | ((unsigned)h[1] << 16);
    lw[p] = (unsigned)l[0] | ((unsigned)l[1] << 16);
  }
  const size_t o = (size_t)e * DM + k0 + ks;
  *(uint4*)(eh + o) = make_uint4(hw[0], hw[1], hw[2], hw[3]);
  *(uint4*)(el + o) = make_uint4(lw[0], lw[1], lw[2], lw[3]);
}

// 256 thr = 4 waves, 16 tokens/block, grid 1024 (4 blocks/CU, 4 waves/SIMD —
// R4 had 1 wave/SIMD at grid 256, occupancy 10.8%, all latency exposed).
// Wave kq = wid: K-quarter dims {r*256 + kq*64 ..+63} per round r; all waves
// share the block's 16-token tile. acc = 4 x f32x4 = 16 VGPR.
// 4-term split MFMA: (uh+ul)*(Eh+El) -> logit err ~2e-6 (R4-verified).
// u: f32 global -> regs -> RNE split -> LDS bf16 planes (dbuf, 2-round prefetch).
// E-frags: direct global->VGPR b128 (L2-resident 512KB, shared by all blocks).
// K-quarter partials -> fin[4][16][68] -> epilogue sums 4.
#define LOAD_U(pf, r) do { _Pragma("unroll") \
  for (int i_ = 0; i_ < 4; ++i_) \
    pf[i_] = *(const float4*)(ugp + (size_t)(r) * RW + i_ * 64); } while (0)

#define WRITE_U(pf, base) do { _Pragma("unroll") \
  for (int i_ = 0; i_ < 4; ++i_) { \
    const float4 v_ = pf[i_]; \
    const unsigned short h0_ = bf16_rne(v_.x), h1_ = bf16_rne(v_.y), \
                         h2_ = bf16_rne(v_.z), h3_ = bf16_rne(v_.w); \
    const unsigned short l0_ = bf16_rne(v_.x - __uint_as_float((unsigned)h0_ << 16)); \
    const unsigned short l1_ = bf16_rne(v_.y - __uint_as_float((unsigned)h1_ << 16)); \
    const unsigned short l2_ = bf16_rne(v_.z - __uint_as_float((unsigned)h2_ << 16)); \
    const unsigned short l3_ = bf16_rne(v_.w - __uint_as_float((unsigned)h3_ << 16)); \
    *(uint2*)&sh[(base) + uoff + i_ * 64] = \
      make_uint2((unsigned)h0_ | ((unsigned)h1_ << 16), (unsigned)h2_ | ((unsigned)h3_ << 16)); \
    *(uint2*)&sh[(base) + PLN + uoff + i_ * 64] = \
      make_uint2((unsigned)l0_ | ((unsigned)l1_ << 16), (unsigned)l2_ | ((unsigned)l3_ << 16)); \
  } } while (0)

#define COMPUTE(r, base) do { _Pragma("unroll") \
  for (int ks_ = 0; ks_ < 2; ++ks_) { \
    const s8v ah_ = *(const s8v*)&sh[(base) + a_off + ks_ * 32]; \
    const s8v al_ = *(const s8v*)&sh[(base) + PLN + a_off + ks_ * 32]; \
    _Pragma("unroll") for (int j_ = 0; j_ < 4; ++j_) { \
      const size_t bo_ = bbase + (size_t)j_ * (16 * DM) + (size_t)(r) * RW + kq * 64 + ks_ * 32; \
      const s8v bh_ = *(const s8v*)&eh[bo_]; \
      const s8v bl_ = *(const s8v*)&el[bo_]; \
      acc[j_] = __builtin_amdgcn_mfma_f32_16x16x32_bf16(ah_, bh_, acc[j_], 0, 0, 0); \
      acc[j_] = __builtin_amdgcn_mfma_f32_16x16x32_bf16(ah_, bl_, acc[j_], 0, 0, 0); \
      acc[j_] = __builtin_amdgcn_mfma_f32_16x16x32_bf16(al_, bh_, acc[j_], 0, 0, 0); \
      acc[j_] = __builtin_amdgcn_mfma_f32_16x16x32_bf16(al_, bl_, acc[j_], 0, 0, 0); \
    } } } while (0)

__global__ __launch_bounds__(256, 4) void router_main_mfma(
    const float* __restrict__ u, const unsigned short* __restrict__ eh,
    const unsigned short* __restrict__ el, const float* __restrict__ bias,
    float* __restrict__ out, float* __restrict__ ws)
{
  __shared__ __align__(16) unsigned short sh[4 * PLN];   // 33,792 B

  const int tid  = threadIdx.x;
  const int lane = tid & 63;
  const int kq   = __builtin_amdgcn_readfirstlane(tid >> 6);  // K-quarter
  const int lm   = lane & 15;          // A: token row / B: expert-in-16
  const int lk   = lane >> 4;          // k-group (8 bf16 each)
  const int tok0 = blockIdx.x * MTPB;

  // u staging: thread -> (token row, 16B f32 seg); 4 segs (i*64 dims) per thread
  const int srow = tid >> 4, sseg = tid & 15;
  const float* ugp = u + (size_t)(tok0 + srow) * DM + sseg * 4;
  const int uoff = srow * RSTR + sseg * 4;     // bf16 elems (+i*64)

  // frag addressing: A row=lane&15, k=(lane>>4)*8+j (B symmetric; R4-verified)
  const int a_off = lm * RSTR + kq * 64 + lk * 8;
  const size_t bbase = (size_t)lm * DM + lk * 8;

  f4v acc[4];
#pragma unroll
  for (int j = 0; j < 4; ++j) acc[j] = (f4v){0.f, 0.f, 0.f, 0.f};

  float4 pfA[4], pfB[4];
  LOAD_U(pfA, 0);
  LOAD_U(pfB, 1);
  WRITE_U(pfA, 0);
  __syncthreads();

  for (int rr = 0; rr < NRND; rr += 2) {
    WRITE_U(pfB, 2 * PLN);                       // round rr+1 -> buf1
    if (rr + 2 < NRND) LOAD_U(pfA, rr + 2);
    COMPUTE(rr, 0);
    __syncthreads();
    if (rr + 2 < NRND) WRITE_U(pfA, 0);          // round rr+2 -> buf0
    if (rr + 3 < NRND) LOAD_U(pfB, rr + 3);
    COMPUTE(rr + 1, 2 * PLN);
    __syncthreads();
  }

  // ---- K-quarter partials: fin[kq][16 tok][68] (aliases sh; 17,408 B) ----
  // D frags: col=lane&15 <-> expert(j*16+lm), row=(lane>>4)*4+reg <-> token.
  float* fin = (float*)sh;
#pragma unroll
  for (int j = 0; j < 4; ++j)
#pragma unroll
    for (int q = 0; q < 4; ++q)
      fin[kq * (16 * 68) + (lk * 4 + q) * 68 + j * 16 + lm] = acc[j][q];
  __syncthreads();

  // ---- epilogue: wave kq -> tokens kq*4..+3, lane = expert (verified) ----
  const float be = bias[lane];
  float asum = 0.f;
#pragma unroll
  for (int tt = 0; tt < 4; ++tt) {
    const int t = kq * 4 + tt;
    float x = fin[t * 68 + lane] + fin[1 * 1088 + t * 68 + lane]
            + fin[2 * 1088 + t * 68 + lane] + fin[3 * 1088 + t * 68 + lane] + be;

    float m = x;
#pragma unroll
    for (int off = 32; off > 0; off >>= 1) m = fmaxf(m, __shfl_xor(m, off));
    float p = expf(x - m);
    float s = p;
#pragma unroll
    for (int off = 32; off > 0; off >>= 1) s += __shfl_xor(s, off);
    float sc = p / s;

    out[OFF_SC + (size_t)(tok0 + t) * NE + lane] = sc;
    asum += sc;

    float v = sc;
#pragma unroll
    for (int k = 0; k < TOPK; ++k) {
      float bv = v;
      int   bi = lane;
#pragma unroll
      for (int off = 32; off > 0; off >>= 1) {
        float ov = __shfl_xor(bv, off);
        int   oi = __shfl_xor(bi, off);
        if (ov > bv || (ov == bv && oi < bi)) { bv = ov; bi = oi; }
      }
      if (lane == k) {
        out[OFF_TI + (size_t)(tok0 + t) * TOPK + k] = (float)bi;
        out[OFF_TS + (size_t)(tok0 + t) * TOPK + k] = bv;
      }
      if (lane == bi) v = -INFINITY;
    }
  }
  atomicAdd(&ws[lane], asum);
}

// ---------------- fallback (ws too small): proven R1 kernel ----------------
#define TPB     64
#define FB_DC   32
#define FB_NCH  (1024 / FB_DC)
#define FB_LSTR 68
#define FB_UB   (TPB * FB_LSTR)
#define FB_EOFF (2 * FB_UB)
#define FB_EB   (2 * FB_DC * NE)

__global__ __launch_bounds__(1024, 4) void router_main_fb(
    const float* __restrict__ u, const float* __restrict__ E,
    const float* __restrict__ bias, float* __restrict__ out,
    float* __restrict__ ws)
{
  __shared__ float smem[FB_EOFF + 2 * FB_EB];

  const int tid  = threadIdx.x;
  const int lane = tid & 63;
  const int wid  = __builtin_amdgcn_readfirstlane(tid >> 6);
  const int eg   = wid & 7;
  const int kh   = wid >> 3;
  const int tok0 = blockIdx.x * TPB;

  const int stok  = tid >> 4;
  const int sdseg = tid & 15;
  const int skh   = sdseg >> 3;
  const int sdsub = (sdseg & 7) * 4;
  const float* sgbase = u + (size_t)(tok0 + stok) * DM + skh * 1024 + sdsub;
  float* swp = smem + stok * FB_LSTR + sdseg * 4;

  const int eq  = tid & 511;
  const int ekh = tid >> 9;
  const float* egbase = E + (size_t)ekh * 1024 * NE + eq * 4;
  float* ewp = smem + FB_EOFF + ekh * (FB_DC * NE) + eq * 4;

  float acc[8];
#pragma unroll
  for (int j = 0; j < 8; ++j) acc[j] = 0.f;

  float4 pf[3];
  pf[0] = *(const float4*)(sgbase + 0 * FB_DC);
  pf[1] = *(const float4*)(sgbase + 1 * FB_DC);
  pf[2] = *(const float4*)(sgbase + 2 * FB_DC);
  float4 epf = *(const float4*)(egbase + 0 * (FB_DC * NE));
  *(float4*)(swp + 0) = pf[0];
  *(float4*)(ewp + 0) = epf;
  epf = *(const float4*)(egbase + 1 * (FB_DC * NE));
  __syncthreads();

  for (int c = 0; c < FB_NCH; ++c) {
    if (c + 1 < FB_NCH) {
      *(float4*)(swp + ((c + 1) & 1) * FB_UB) = pf[(c + 1) % 3];
      *(float4*)(ewp + ((c + 1) & 1) * FB_EB) = epf;
    }
    if (c + 2 < FB_NCH)
      epf = *(const float4*)(egbase + (c + 2) * (FB_DC * NE));
    if (c + 3 < FB_NCH)
      pf[c % 3] = *(const float4*)(sgbase + (c + 3) * FB_DC);

    const float* sb = smem + (c & 1) * FB_UB + lane * FB_LSTR + kh * FB_DC;
    const float* eb = smem + FB_EOFF + (c & 1) * FB_EB + kh * (FB_DC * NE) + eg * 8;
#pragma unroll
    for (int s = 0; s < 8; ++s) {
      float4 uf = *(const float4*)(sb + s * 4);
#pragma unroll
      for (int dd = 0; dd < 4; ++dd) {
        const float* er = eb + (s * 4 + dd) * NE;
        float4 e0 = *(const float4*)(er);
        float4 e1 = *(const float4*)(er + 4);
        const float uv = (&uf.x)[dd];
        acc[0] = fmaf(e0.x, uv, acc[0]);
        acc[1] = fmaf(e0.y, uv, acc[1]);
        acc[2] = fmaf(e0.z, uv, acc[2]);
        acc[3] = fmaf(e0.w, uv, acc[3]);
        acc[4] = fmaf(e1.x, uv, acc[4]);
        acc[5] = fmaf(e1.y, uv, acc[5]);
        acc[6] = fmaf(e1.z, uv, acc[6]);
        acc[7] = fmaf(e1.w, uv, acc[7]);
      }
    }
    __syncthreads();
  }

  float* fin = smem;
  if (kh == 0) {
#pragma unroll
    for (int j = 0; j < 8; ++j) fin[lane * 65 + eg * 8 + j] = acc[j];
  }
  __syncthreads();
  if (kh == 1) {
#pragma unroll
    for (int j = 0; j < 8; ++j) fin[lane * 65 + eg * 8 + j] += acc[j];
  }
  __syncthreads();

  const float be = bias[lane];
  float asum = 0.f;
#pragma unroll
  for (int tt = 0; tt < 4; ++tt) {
    const int t = wid * 4 + tt;
    float x = fin[t * 65 + lane] + be;

    float m = x;
#pragma unroll
    for (int off = 32; off > 0; off >>= 1) m = fmaxf(m, __shfl_xor(m, off));
    float p = expf(x - m);
    float s = p;
#pragma unroll
    for (int off = 32; off > 0; off >>= 1) s += __shfl_xor(s, off);
    float sc = p / s;

    out[OFF_SC + (size_t)(tok0 + t) * NE + lane] = sc;
    asum += sc;

    float v = sc;
#pragma unroll
    for (int k = 0; k < TOPK; ++k) {
      float bv = v;
      int   bi = lane;
#pragma unroll
      for (int off = 32; off > 0; off >>= 1) {
        float ov = __shfl_xor(bv, off);
        int   oi = __shfl_xor(bi, off);
        if (ov > bv || (ov == bv && oi < bi)) { bv = ov; bi = oi; }
      }
      if (lane == k) {
        out[OFF_TI + (size_t)(tok0 + t) * TOPK + k] = (float)bi;
        out[OFF_TS + (size_t)(tok0 + t) * TOPK + k] = bv;
      }
      if (lane == bi) v = -INFINITY;
    }
  }
  atomicAdd(&ws[lane], asum);
}

__global__ void router_aux(const float* __restrict__ ws, float* __restrict__ out)
{
  const int lane = threadIdx.x & 63;
  float m = ws[lane] * (1.0f / N_TOK);
  float v = m * m;
#pragma unroll
  for (int off = 32; off > 0; off >>= 1) v += __shfl_xor(v, off);
  if (lane == 0) out[OFF_AUX] = v * (float)NE;
}

extern "C" void kernel_launch(void* const* d_in, const int* in_sizes, int n_in,
                              void* d_out, int out_size, void* d_ws, size_t ws_size,
                              hipStream_t stream) {
  const float* u    = (const float*)d_in[0];
  const float* E    = (const float*)d_in[1];
  const float* bias = (const float*)d_in[2];
  float* out = (float*)d_out;
  float* ws  = (float*)d_ws;

  hipMemsetAsync(ws, 0, NE * sizeof(float), stream);
  if (ws_size >= WS_NEED) {
    unsigned short* eh = (unsigned short*)((char*)ws + EH_OFF);
    unsigned short* el = eh + ET_ELEMS;
    router_prep<<<DM / 32, 256, 0, stream>>>(E, eh, el);
    router_main_mfma<<<N_TOK / MTPB, 256, 0, stream>>>(u, eh, el, bias, out, ws);
  } else {
    router_main_fb<<<N_TOK / TPB, 1024, 0, stream>>>(u, E, bias, out, ws);
  }
  router_aux<<<1, 64, 0, stream>>>(ws, out);
}

// Round 6
// 313.659 us; speedup vs baseline: 1.0495x; 1.0495x over previous
//
#include <hip/hip_runtime.h>
#include <math.h>

#define N_TOK 16384
#define DM    2048
#define NE    64
#define TOPK  4

#define OFF_TI  0
#define OFF_TS  (N_TOK * TOPK)
#define OFF_SC  (2 * N_TOK * TOPK)
#define OFF_AUX (2 * N_TOK * TOPK + N_TOK * NE)

// ---------------- MFMA path ----------------
#define MTPB  16             // tokens per block -> grid 1024 = 4 blocks/CU
#define RW    256            // dims per staged round (4 waves x 64)
#define NRND  (DM / RW)      // 8
#define RSTR  264            // u bf16 plane row stride (528B: bank-balanced b128)
#define PLN   (MTPB * RSTR)  // 4224 bf16 per plane
                             // buffers: [buf][hi PLN][lo PLN], 2 bufs = 33792 B

#define EH_OFF   1024                      // byte offset of packed Eh in ws
#define ET_ELEMS ((size_t)NE * DM)         // 131072 bf16 per table
#define WS_NEED  (EH_OFF + 4 * ET_ELEMS)   // 525,312 B

typedef short s8v __attribute__((ext_vector_type(8)));   // 8 bf16 = 4 VGPR
typedef float f4v __attribute__((ext_vector_type(4)));

__device__ __forceinline__ unsigned short bf16_rne(float x) {
  unsigned int b = __float_as_uint(x);
  b += 0x7FFFu + ((b >> 16) & 1u);
  return (unsigned short)(b >> 16);
}

// E[2048][64] f32 -> PACKED B-fragment layout, split hi/lo bf16:
//   EP[pk][j][lane][q]: pk = k-block of 32 dims (64 total), j = expert group,
//   lane = MFMA B-lane (expert = j*16 + (lane&15), k = pk*32 + (lane>>4)*8 + q).
// A wave's B-frag load is then 64 lanes x 16B CONTIGUOUS (1KB) — R5's
// expert-major layout made each b128 touch 16 lines 4KB apart; that VMEM
// transaction count (2048 instr x 16 lines per CU) was the measured 184us
// wall, invariant to occupancy (R4 vs R5).
__global__ __launch_bounds__(256) void router_prep(
    const float* __restrict__ E, unsigned short* __restrict__ eh,
    unsigned short* __restrict__ el)
{
  __shared__ float t[32][65];
  const int tid = threadIdx.x;
  const int k0  = blockIdx.x * 32;          // = pk * 32
#pragma unroll
  for (int i = 0; i < 2; ++i) {
    const int fi = i * 256 + tid;
    const int kk = fi >> 4, ee = (fi & 15) * 4;
    const float4 v = *(const float4*)(E + (size_t)(k0 + kk) * NE + ee);
    t[kk][ee] = v.x; t[kk][ee + 1] = v.y; t[kk][ee + 2] = v.z; t[kk][ee + 3] = v.w;
  }
  __syncthreads();
  const int j    = tid >> 6;                // expert group
  const int lane = tid & 63;                // B-lane
  const int ex   = j * 16 + (lane & 15);    // expert
  const int kb   = (lane >> 4) * 8;         // k offset within block
  unsigned int hw[4], lw[4];
#pragma unroll
  for (int p = 0; p < 4; ++p) {
    unsigned short h[2], l[2];
#pragma unroll
    for (int q = 0; q < 2; ++q) {
      const float x = t[kb + p * 2 + q][ex];
      h[q] = bf16_rne(x);
      l[q] = bf16_rne(x - __uint_as_float((unsigned)h[q] << 16));
    }
    hw[p] = (unsigned)h[0] | ((unsigned)h[1] << 16);
    lw[p] = (unsigned)l[0] | ((unsigned)l[1] << 16);
  }
  const size_t o = (size_t)blockIdx.x * 2048 + j * 512 + lane * 8;
  *(uint4*)(eh + o) = make_uint4(hw[0], hw[1], hw[2], hw[3]);
  *(uint4*)(el + o) = make_uint4(lw[0], lw[1], lw[2], lw[3]);
}

// 256 thr = 4 waves, 16 tokens/block, grid 1024 (4 blocks/CU, 4 waves/SIMD).
// Wave kq: K-quarter dims {r*256 + kq*64 ..+63} per round r. acc = 16 VGPR.
// 4-term split MFMA: (uh+ul)*(Eh+El) -> logit err ~2e-6 (R4-verified).
// u: f32 global -> regs -> RNE split -> LDS bf16 planes (dbuf, 2-round prefetch).
// E-frags: packed-coalesced global->VGPR b128 (1KB/wave/instr, L2-resident).
#define LOAD_U(pf, r) do { _Pragma("unroll") \
  for (int i_ = 0; i_ < 4; ++i_) \
    pf[i_] = *(const float4*)(ugp + (size_t)(r) * RW + i_ * 64); } while (0)

#define WRITE_U(pf, base) do { _Pragma("unroll") \
  for (int i_ = 0; i_ < 4; ++i_) { \
    const float4 v_ = pf[i_]; \
    const unsigned short h0_ = bf16_rne(v_.x), h1_ = bf16_rne(v_.y), \
                         h2_ = bf16_rne(v_.z), h3_ = bf16_rne(v_.w); \
    const unsigned short l0_ = bf16_rne(v_.x - __uint_as_float((unsigned)h0_ << 16)); \
    const unsigned short l1_ = bf16_rne(v_.y - __uint_as_float((unsigned)h1_ << 16)); \
    const unsigned short l2_ = bf16_rne(v_.z - __uint_as_float((unsigned)h2_ << 16)); \
    const unsigned short l3_ = bf16_rne(v_.w - __uint_as_float((unsigned)h3_ << 16)); \
    *(uint2*)&sh[(base) + uoff + i_ * 64] = \
      make_uint2((unsigned)h0_ | ((unsigned)h1_ << 16), (unsigned)h2_ | ((unsigned)h3_ << 16)); \
    *(uint2*)&sh[(base) + PLN + uoff + i_ * 64] = \
      make_uint2((unsigned)l0_ | ((unsigned)l1_ << 16), (unsigned)l2_ | ((unsigned)l3_ << 16)); \
  } } while (0)

// pk = r*8 + kq*2 + ks_ ; packed frag base = pk*2048 + j_*512 + lane*8
#define COMPUTE(r, base) do { _Pragma("unroll") \
  for (int ks_ = 0; ks_ < 2; ++ks_) { \
    const s8v ah_ = *(const s8v*)&sh[(base) + a_off + ks_ * 32]; \
    const s8v al_ = *(const s8v*)&sh[(base) + PLN + a_off + ks_ * 32]; \
    const size_t pb_ = (size_t)(((r) * 8 + kq * 2 + ks_) * 2048) + lane * 8; \
    _Pragma("unroll") for (int j_ = 0; j_ < 4; ++j_) { \
      const s8v bh_ = *(const s8v*)&eh[pb_ + j_ * 512]; \
      const s8v bl_ = *(const s8v*)&el[pb_ + j_ * 512]; \
      acc[j_] = __builtin_amdgcn_mfma_f32_16x16x32_bf16(ah_, bh_, acc[j_], 0, 0, 0); \
      acc[j_] = __builtin_amdgcn_mfma_f32_16x16x32_bf16(ah_, bl_, acc[j_], 0, 0, 0); \
      acc[j_] = __builtin_amdgcn_mfma_f32_16x16x32_bf16(al_, bh_, acc[j_], 0, 0, 0); \
      acc[j_] = __builtin_amdgcn_mfma_f32_16x16x32_bf16(al_, bl_, acc[j_], 0, 0, 0); \
    } } } while (0)

__global__ __launch_bounds__(256, 4) void router_main_mfma(
    const float* __restrict__ u, const unsigned short* __restrict__ eh,
    const unsigned short* __restrict__ el, const float* __restrict__ bias,
    float* __restrict__ out, float* __restrict__ ws)
{
  __shared__ __align__(16) unsigned short sh[4 * PLN];   // 33,792 B

  const int tid  = threadIdx.x;
  const int lane = tid & 63;
  const int kq   = __builtin_amdgcn_readfirstlane(tid >> 6);  // K-quarter
  const int lm   = lane & 15;          // A: token row
  const int lk   = lane >> 4;          // k-group (8 bf16 each)
  const int tok0 = blockIdx.x * MTPB;

  // u staging: thread -> (token row, 16B f32 seg); 4 segs (i*64 dims) per thread
  const int srow = tid >> 4, sseg = tid & 15;
  const float* ugp = u + (size_t)(tok0 + srow) * DM + sseg * 4;
  const int uoff = srow * RSTR + sseg * 4;     // bf16 elems (+i*64)

  // A-frag: row=lane&15, k=(lane>>4)*8+j (R4-verified)
  const int a_off = lm * RSTR + kq * 64 + lk * 8;

  f4v acc[4];
#pragma unroll
  for (int j = 0; j < 4; ++j) acc[j] = (f4v){0.f, 0.f, 0.f, 0.f};

  float4 pfA[4], pfB[4];
  LOAD_U(pfA, 0);
  LOAD_U(pfB, 1);
  WRITE_U(pfA, 0);
  __syncthreads();

  for (int rr = 0; rr < NRND; rr += 2) {
    WRITE_U(pfB, 2 * PLN);                       // round rr+1 -> buf1
    if (rr + 2 < NRND) LOAD_U(pfA, rr + 2);
    COMPUTE(rr, 0);
    __syncthreads();
    if (rr + 2 < NRND) WRITE_U(pfA, 0);          // round rr+2 -> buf0
    if (rr + 3 < NRND) LOAD_U(pfB, rr + 3);
    COMPUTE(rr + 1, 2 * PLN);
    __syncthreads();
  }

  // ---- K-quarter partials: fin[kq][16 tok][68] (aliases sh; 17,408 B) ----
  // D frags: col=lane&15 <-> expert(j*16+lm), row=(lane>>4)*4+reg <-> token.
  float* fin = (float*)sh;
#pragma unroll
  for (int j = 0; j < 4; ++j)
#pragma unroll
    for (int q = 0; q < 4; ++q)
      fin[kq * (16 * 68) + (lk * 4 + q) * 68 + j * 16 + lm] = acc[j][q];
  __syncthreads();

  // ---- epilogue: wave kq -> tokens kq*4..+3, lane = expert (verified) ----
  const float be = bias[lane];
  float asum = 0.f;
#pragma unroll
  for (int tt = 0; tt < 4; ++tt) {
    const int t = kq * 4 + tt;
    float x = fin[t * 68 + lane] + fin[1 * 1088 + t * 68 + lane]
            + fin[2 * 1088 + t * 68 + lane] + fin[3 * 1088 + t * 68 + lane] + be;

    float m = x;
#pragma unroll
    for (int off = 32; off > 0; off >>= 1) m = fmaxf(m, __shfl_xor(m, off));
    float p = expf(x - m);
    float s = p;
#pragma unroll
    for (int off = 32; off > 0; off >>= 1) s += __shfl_xor(s, off);
    float sc = p / s;

    out[OFF_SC + (size_t)(tok0 + t) * NE + lane] = sc;
    asum += sc;

    float v = sc;
#pragma unroll
    for (int k = 0; k < TOPK; ++k) {
      float bv = v;
      int   bi = lane;
#pragma unroll
      for (int off = 32; off > 0; off >>= 1) {
        float ov = __shfl_xor(bv, off);
        int   oi = __shfl_xor(bi, off);
        if (ov > bv || (ov == bv && oi < bi)) { bv = ov; bi = oi; }
      }
      if (lane == k) {
        out[OFF_TI + (size_t)(tok0 + t) * TOPK + k] = (float)bi;
        out[OFF_TS + (size_t)(tok0 + t) * TOPK + k] = bv;
      }
      if (lane == bi) v = -INFINITY;
    }
  }
  atomicAdd(&ws[lane], asum);
}

// ---------------- fallback (ws too small): proven R1 kernel ----------------
#define TPB     64
#define FB_DC   32
#define FB_NCH  (1024 / FB_DC)
#define FB_LSTR 68
#define FB_UB   (TPB * FB_LSTR)
#define FB_EOFF (2 * FB_UB)
#define FB_EB   (2 * FB_DC * NE)

__global__ __launch_bounds__(1024, 4) void router_main_fb(
    const float* __restrict__ u, const float* __restrict__ E,
    const float* __restrict__ bias, float* __restrict__ out,
    float* __restrict__ ws)
{
  __shared__ float smem[FB_EOFF + 2 * FB_EB];

  const int tid  = threadIdx.x;
  const int lane = tid & 63;
  const int wid  = __builtin_amdgcn_readfirstlane(tid >> 6);
  const int eg   = wid & 7;
  const int kh   = wid >> 3;
  const int tok0 = blockIdx.x * TPB;

  const int stok  = tid >> 4;
  const int sdseg = tid & 15;
  const int skh   = sdseg >> 3;
  const int sdsub = (sdseg & 7) * 4;
  const float* sgbase = u + (size_t)(tok0 + stok) * DM + skh * 1024 + sdsub;
  float* swp = smem + stok * FB_LSTR + sdseg * 4;

  const int eq  = tid & 511;
  const int ekh = tid >> 9;
  const float* egbase = E + (size_t)ekh * 1024 * NE + eq * 4;
  float* ewp = smem + FB_EOFF + ekh * (FB_DC * NE) + eq * 4;

  float acc[8];
#pragma unroll
  for (int j = 0; j < 8; ++j) acc[j] = 0.f;

  float4 pf[3];
  pf[0] = *(const float4*)(sgbase + 0 * FB_DC);
  pf[1] = *(const float4*)(sgbase + 1 * FB_DC);
  pf[2] = *(const float4*)(sgbase + 2 * FB_DC);
  float4 epf = *(const float4*)(egbase + 0 * (FB_DC * NE));
  *(float4*)(swp + 0) = pf[0];
  *(float4*)(ewp + 0) = epf;
  epf = *(const float4*)(egbase + 1 * (FB_DC * NE));
  __syncthreads();

  for (int c = 0; c < FB_NCH; ++c) {
    if (c + 1 < FB_NCH) {
      *(float4*)(swp + ((c + 1) & 1) * FB_UB) = pf[(c + 1) % 3];
      *(float4*)(ewp + ((c + 1) & 1) * FB_EB) = epf;
    }
    if (c + 2 < FB_NCH)
      epf = *(const float4*)(egbase + (c + 2) * (FB_DC * NE));
    if (c + 3 < FB_NCH)
      pf[c % 3] = *(const float4*)(sgbase + (c + 3) * FB_DC);

    const float* sb = smem + (c & 1) * FB_UB + lane * FB_LSTR + kh * FB_DC;
    const float* eb = smem + FB_EOFF + (c & 1) * FB_EB + kh * (FB_DC * NE) + eg * 8;
#pragma unroll
    for (int s = 0; s < 8; ++s) {
      float4 uf = *(const float4*)(sb + s * 4);
#pragma unroll
      for (int dd = 0; dd < 4; ++dd) {
        const float* er = eb + (s * 4 + dd) * NE;
        float4 e0 = *(const float4*)(er);
        float4 e1 = *(const float4*)(er + 4);
        const float uv = (&uf.x)[dd];
        acc[0] = fmaf(e0.x, uv, acc[0]);
        acc[1] = fmaf(e0.y, uv, acc[1]);
        acc[2] = fmaf(e0.z, uv, acc[2]);
        acc[3] = fmaf(e0.w, uv, acc[3]);
        acc[4] = fmaf(e1.x, uv, acc[4]);
        acc[5] = fmaf(e1.y, uv, acc[5]);
        acc[6] = fmaf(e1.z, uv, acc[6]);
        acc[7] = fmaf(e1.w, uv, acc[7]);
      }
    }
    __syncthreads();
  }

  float* fin = smem;
  if (kh == 0) {
#pragma unroll
    for (int j = 0; j < 8; ++j) fin[lane * 65 + eg * 8 + j] = acc[j];
  }
  __syncthreads();
  if (kh == 1) {
#pragma unroll
    for (int j = 0; j < 8; ++j) fin[lane * 65 + eg * 8 + j] += acc[j];
  }
  __syncthreads();

  const float be = bias[lane];
  float asum = 0.f;
#pragma unroll
  for (int tt = 0; tt < 4; ++tt) {
    const int t = wid * 4 + tt;
    float x = fin[t * 65 + lane] + be;

    float m = x;
#pragma unroll
    for (int off = 32; off > 0; off >>= 1) m = fmaxf(m, __shfl_xor(m, off));
    float p = expf(x - m);
    float s = p;
#pragma unroll
    for (int off = 32; off > 0; off >>= 1) s += __shfl_xor(s, off);
    float sc = p / s;

    out[OFF_SC + (size_t)(tok0 + t) * NE + lane] = sc;
    asum += sc;

    float v = sc;
#pragma unroll
    for (int k = 0; k < TOPK; ++k) {
      float bv = v;
      int   bi = lane;
#pragma unroll
      for (int off = 32; off > 0; off >>= 1) {
        float ov = __shfl_xor(bv, off);
        int   oi = __shfl_xor(bi, off);
        if (ov > bv || (ov == bv && oi < bi)) { bv = ov; bi = oi; }
      }
      if (lane == k) {
        out[OFF_TI + (size_t)(tok0 + t) * TOPK + k] = (float)bi;
        out[OFF_TS + (size_t)(tok0 + t) * TOPK + k] = bv;
      }
      if (lane == bi) v = -INFINITY;
    }
  }
  atomicAdd(&ws[lane], asum);
}

__global__ void router_aux(const float* __restrict__ ws, float* __restrict__ out)
{
  const int lane = threadIdx.x & 63;
  float m = ws[lane] * (1.0f / N_TOK);
  float v = m * m;
#pragma unroll
  for (int off = 32; off > 0; off >>= 1) v += __shfl_xor(v, off);
  if (lane == 0) out[OFF_AUX] = v * (float)NE;
}

extern "C" void kernel_launch(void* const* d_in, const int* in_sizes, int n_in,
                              void* d_out, int out_size, void* d_ws, size_t ws_size,
                              hipStream_t stream) {
  const float* u    = (const float*)d_in[0];
  const float* E    = (const float*)d_in[1];
  const float* bias = (const float*)d_in[2];
  float* out = (float*)d_out;
  float* ws  = (float*)d_ws;

  hipMemsetAsync(ws, 0, NE * sizeof(float), stream);
  if (ws_size >= WS_NEED) {
    unsigned short* eh = (unsigned short*)((char*)ws + EH_OFF);
    unsigned short* el = eh + ET_ELEMS;
    router_prep<<<DM / 32, 256, 0, stream>>>(E, eh, el);
    router_main_mfma<<<N_TOK / MTPB, 256, 0, stream>>>(u, eh, el, bias, out, ws);
  } else {
    router_main_fb<<<N_TOK / TPB, 1024, 0, stream>>>(u, E, bias, out, ws);
  }
  router_aux<<<1, 64, 0, stream>>>(ws, out);
}

// Round 7
// 273.566 us; speedup vs baseline: 1.2033x; 1.1466x over previous
//
#include <hip/hip_runtime.h>
#include <math.h>

#define N_TOK 16384
#define DM    2048
#define NE    64
#define TOPK  4

#define OFF_TI  0
#define OFF_TS  (N_TOK * TOPK)
#define OFF_SC  (2 * N_TOK * TOPK)
#define OFF_AUX (2 * N_TOK * TOPK + N_TOK * NE)

// ---------------- MFMA path ----------------
#define MTPB  64             // tokens per block -> grid 256 = 1 block/CU
#define RW    128            // dims per staged round
#define NRND  (DM / RW)      // 16
#define KSTR  136            // u bf16 plane row stride (128 + 8 pad)
#define PLN   (MTPB * KSTR)  // 8704 bf16 per plane (17408 B)
                             // LDS: buf b -> hi at 2b*PLN, lo at (2b+1)*PLN

#define EH_OFF   1024                      // byte offset of packed Eh in ws
#define ET_ELEMS ((size_t)NE * DM)         // 131072 bf16 per table
#define WS_NEED  (EH_OFF + 4 * ET_ELEMS)   // 525,312 B

typedef short s8v __attribute__((ext_vector_type(8)));   // 8 bf16 = 4 VGPR
typedef float f4v __attribute__((ext_vector_type(4)));

__device__ __forceinline__ unsigned short bf16_rne(float x) {
  unsigned int b = __float_as_uint(x);
  b += 0x7FFFu + ((b >> 16) & 1u);
  return (unsigned short)(b >> 16);
}

// E[2048][64] f32 -> PACKED B-fragment layout (R6-verified), split hi/lo bf16:
//   EP[pk][j][lane][q]: expert = j*16+(lane&15), k = pk*32+(lane>>4)*8+q.
// Also zeroes ws[0..127] (per-expert partials + ticket counter) so the
// separate hipMemsetAsync dispatch is not needed (4 dispatches -> 2; the
// fixed non-main time has been ~144us across R0-R6).
__global__ __launch_bounds__(256) void router_prep(
    const float* __restrict__ E, unsigned short* __restrict__ eh,
    unsigned short* __restrict__ el, float* __restrict__ ws)
{
  __shared__ float t[32][65];
  const int tid = threadIdx.x;
  if (blockIdx.x == 0 && tid < 128) ws[tid] = 0.f;
  const int k0  = blockIdx.x * 32;          // = pk * 32
#pragma unroll
  for (int i = 0; i < 2; ++i) {
    const int fi = i * 256 + tid;
    const int kk = fi >> 4, ee = (fi & 15) * 4;
    const float4 v = *(const float4*)(E + (size_t)(k0 + kk) * NE + ee);
    t[kk][ee] = v.x; t[kk][ee + 1] = v.y; t[kk][ee + 2] = v.z; t[kk][ee + 3] = v.w;
  }
  __syncthreads();
  const int j    = tid >> 6;                // expert group
  const int lane = tid & 63;                // B-lane
  const int ex   = j * 16 + (lane & 15);    // expert
  const int kb   = (lane >> 4) * 8;         // k offset within block
  unsigned int hw[4], lw[4];
#pragma unroll
  for (int p = 0; p < 4; ++p) {
    unsigned short h[2], l[2];
#pragma unroll
    for (int q = 0; q < 2; ++q) {
      const float x = t[kb + p * 2 + q][ex];
      h[q] = bf16_rne(x);
      l[q] = bf16_rne(x - __uint_as_float((unsigned)h[q] << 16));
    }
    hw[p] = (unsigned)h[0] | ((unsigned)h[1] << 16);
    lw[p] = (unsigned)l[0] | ((unsigned)l[1] << 16);
  }
  const size_t o = (size_t)blockIdx.x * 2048 + j * 512 + lane * 8;
  *(uint4*)(eh + o) = make_uint4(hw[0], hw[1], hw[2], hw[3]);
  *(uint4*)(el + o) = make_uint4(lw[0], lw[1], lw[2], lw[3]);
}

// 256 thr = 4 waves, 64 tokens/block, grid 256 (1 block/CU).
// Measured law (R4=R5=R6 ~170-185us, invariant to occupancy AND coalescing):
// time ~= E-load instructions per CU x ~200cyc. This round: each (bh,bl)
// pair feeds 4 token-tiles x 4 split-terms = 16 MFMAs; E-instr/CU 2048->512.
// Wave kq: dims {r*128 + kq*32 ..+31} per round r (pk = r*4+kq).
// acc[4 tile][4 j] f4v = 64 VGPR; 4-term split (R4-verified numerics).
// fin reduction: waves 0,1 write planes, waves 2,3 add, epilogue sums 2.
// aux-loss folded in via last-block ticket (removes router_aux dispatch).
#define LOAD_U(pf, r) do { _Pragma("unroll") \
  for (int i_ = 0; i_ < 8; ++i_) \
    pf[i_] = *(const float4*)(ugp + (size_t)(r) * RW + i_ * 16); } while (0)

#define WRITE_U(pf, base) do { _Pragma("unroll") \
  for (int i_ = 0; i_ < 8; ++i_) { \
    const float4 v_ = pf[i_]; \
    const unsigned short h0_ = bf16_rne(v_.x), h1_ = bf16_rne(v_.y), \
                         h2_ = bf16_rne(v_.z), h3_ = bf16_rne(v_.w); \
    const unsigned short l0_ = bf16_rne(v_.x - __uint_as_float((unsigned)h0_ << 16)); \
    const unsigned short l1_ = bf16_rne(v_.y - __uint_as_float((unsigned)h1_ << 16)); \
    const unsigned short l2_ = bf16_rne(v_.z - __uint_as_float((unsigned)h2_ << 16)); \
    const unsigned short l3_ = bf16_rne(v_.w - __uint_as_float((unsigned)h3_ << 16)); \
    *(uint2*)&sh[(base) + uoff + i_ * 16] = \
      make_uint2((unsigned)h0_ | ((unsigned)h1_ << 16), (unsigned)h2_ | ((unsigned)h3_ << 16)); \
    *(uint2*)&sh[(base) + PLN + uoff + i_ * 16] = \
      make_uint2((unsigned)l0_ | ((unsigned)l1_ << 16), (unsigned)l2_ | ((unsigned)l3_ << 16)); \
  } } while (0)

#define COMPUTE(r, base) do { \
    const int    pk_ = (r) * 4 + kq; \
    const size_t pb_ = (size_t)pk_ * 2048 + lane * 8; \
    s8v ah_[4], al_[4]; \
    _Pragma("unroll") for (int tt_ = 0; tt_ < 4; ++tt_) { \
      ah_[tt_] = *(const s8v*)&sh[(base) + a_off + tt_ * (16 * KSTR)]; \
      al_[tt_] = *(const s8v*)&sh[(base) + PLN + a_off + tt_ * (16 * KSTR)]; \
    } \
    _Pragma("unroll") for (int j_ = 0; j_ < 4; ++j_) { \
      const s8v bh_ = *(const s8v*)&eh[pb_ + j_ * 512]; \
      const s8v bl_ = *(const s8v*)&el[pb_ + j_ * 512]; \
      _Pragma("unroll") for (int tt_ = 0; tt_ < 4; ++tt_) { \
        acc[tt_][j_] = __builtin_amdgcn_mfma_f32_16x16x32_bf16(ah_[tt_], bh_, acc[tt_][j_], 0, 0, 0); \
        acc[tt_][j_] = __builtin_amdgcn_mfma_f32_16x16x32_bf16(ah_[tt_], bl_, acc[tt_][j_], 0, 0, 0); \
        acc[tt_][j_] = __builtin_amdgcn_mfma_f32_16x16x32_bf16(al_[tt_], bh_, acc[tt_][j_], 0, 0, 0); \
        acc[tt_][j_] = __builtin_amdgcn_mfma_f32_16x16x32_bf16(al_[tt_], bl_, acc[tt_][j_], 0, 0, 0); \
      } } } while (0)

__global__ __launch_bounds__(256, 1) void router_main_mfma(
    const float* __restrict__ u, const unsigned short* __restrict__ eh,
    const unsigned short* __restrict__ el, const float* __restrict__ bias,
    float* __restrict__ out, float* __restrict__ ws)
{
  __shared__ __align__(16) unsigned short sh[4 * PLN];   // 69,632 B

  const int tid  = threadIdx.x;
  const int lane = tid & 63;
  const int kq   = __builtin_amdgcn_readfirstlane(tid >> 6);  // K-quarter of round
  const int lm   = lane & 15;          // A: token row
  const int lk   = lane >> 4;          // k-group (8 bf16 each)
  const int tok0 = blockIdx.x * MTPB;

  // u staging: thread -> (token row, 16B f32 seg); 8 segs (i*64B) per thread
  const int srow = tid >> 2, sseg = tid & 3;
  const float* ugp = u + (size_t)(tok0 + srow) * DM + sseg * 4;
  const int uoff = srow * KSTR + sseg * 4;     // bf16 elems (+i*16)

  // A-frag: row=lane&15, k=(lane>>4)*8+j (R4-verified); +tt*16 rows per tile
  const int a_off = lm * KSTR + kq * 32 + lk * 8;

  f4v acc[4][4];
#pragma unroll
  for (int t = 0; t < 4; ++t)
#pragma unroll
    for (int j = 0; j < 4; ++j) acc[t][j] = (f4v){0.f, 0.f, 0.f, 0.f};

  float4 pfA[8], pfB[8];
  LOAD_U(pfA, 0);
  LOAD_U(pfB, 1);
  WRITE_U(pfA, 0);
  __syncthreads();

  for (int rr = 0; rr < NRND; rr += 2) {
    WRITE_U(pfB, 2 * PLN);                       // round rr+1 -> buf1
    if (rr + 2 < NRND) LOAD_U(pfA, rr + 2);
    COMPUTE(rr, 0);
    __syncthreads();
    if (rr + 2 < NRND) WRITE_U(pfA, 0);          // round rr+2 -> buf0
    if (rr + 3 < NRND) LOAD_U(pfB, rr + 3);
    COMPUTE(rr + 1, 2 * PLN);
    __syncthreads();
  }

  // ---- K-partials: fin[2][64 tok][68] (aliases buf0, 34,816 B) ----
  // D frags: col=lane&15 <-> expert(j*16+lm), row=lk*4+q <-> token (tt*16+).
  float* fin = (float*)sh;
  if (kq < 2) {
#pragma unroll
    for (int t = 0; t < 4; ++t)
#pragma unroll
      for (int j = 0; j < 4; ++j)
#pragma unroll
        for (int q = 0; q < 4; ++q)
          fin[kq * (64 * 68) + (t * 16 + lk * 4 + q) * 68 + j * 16 + lm] = acc[t][j][q];
  }
  __syncthreads();
  if (kq >= 2) {
#pragma unroll
    for (int t = 0; t < 4; ++t)
#pragma unroll
      for (int j = 0; j < 4; ++j)
#pragma unroll
        for (int q = 0; q < 4; ++q)
          fin[(kq - 2) * (64 * 68) + (t * 16 + lk * 4 + q) * 68 + j * 16 + lm] += acc[t][j][q];
  }
  __syncthreads();

  // ---- epilogue: wave kq -> tokens kq*16..+15, lane = expert (verified) ----
  const float be = bias[lane];
  float asum = 0.f;
  for (int tt = 0; tt < 16; ++tt) {
    const int t = kq * 16 + tt;
    float x = fin[t * 68 + lane] + fin[64 * 68 + t * 68 + lane] + be;

    float m = x;
#pragma unroll
    for (int off = 32; off > 0; off >>= 1) m = fmaxf(m, __shfl_xor(m, off));
    float p = expf(x - m);
    float s = p;
#pragma unroll
    for (int off = 32; off > 0; off >>= 1) s += __shfl_xor(s, off);
    float sc = p / s;

    out[OFF_SC + (size_t)(tok0 + t) * NE + lane] = sc;
    asum += sc;

    float v = sc;
#pragma unroll
    for (int k = 0; k < TOPK; ++k) {
      float bv = v;
      int   bi = lane;
#pragma unroll
      for (int off = 32; off > 0; off >>= 1) {
        float ov = __shfl_xor(bv, off);
        int   oi = __shfl_xor(bi, off);
        if (ov > bv || (ov == bv && oi < bi)) { bv = ov; bi = oi; }
      }
      if (lane == k) {
        out[OFF_TI + (size_t)(tok0 + t) * TOPK + k] = (float)bi;
        out[OFF_TS + (size_t)(tok0 + t) * TOPK + k] = bv;
      }
      if (lane == bi) v = -INFINITY;
    }
  }
  atomicAdd(&ws[lane], asum);   // per-expert partial for aux loss

  // ---- folded aux: last block to finish reduces ws (device-scope ticket) ----
  __threadfence();              // each thread: own atomic visible before ticket
  __syncthreads();
  unsigned* flg = (unsigned*)sh;
  if (tid == 0) {
    const unsigned t = atomicAdd((unsigned*)&ws[NE], 1u);   // ws[64] = counter
    flg[9216] = (t == (unsigned)(gridDim.x - 1)) ? 1u : 0u;
  }
  __syncthreads();
  if (flg[9216] && tid < 64) {
    const float mv = atomicAdd(&ws[tid], 0.f) * (1.0f / N_TOK);  // coherent read
    float v = mv * mv;
#pragma unroll
    for (int off = 32; off > 0; off >>= 1) v += __shfl_xor(v, off);
    if (tid == 0) out[OFF_AUX] = v * (float)NE;
  }
}

// ---------------- fallback (ws too small): proven R1 kernel ----------------
#define TPB     64
#define FB_DC   32
#define FB_NCH  (1024 / FB_DC)
#define FB_LSTR 68
#define FB_UB   (TPB * FB_LSTR)
#define FB_EOFF (2 * FB_UB)
#define FB_EB   (2 * FB_DC * NE)

__global__ __launch_bounds__(1024, 4) void router_main_fb(
    const float* __restrict__ u, const float* __restrict__ E,
    const float* __restrict__ bias, float* __restrict__ out,
    float* __restrict__ ws)
{
  __shared__ float smem[FB_EOFF + 2 * FB_EB];

  const int tid  = threadIdx.x;
  const int lane = tid & 63;
  const int wid  = __builtin_amdgcn_readfirstlane(tid >> 6);
  const int eg   = wid & 7;
  const int kh   = wid >> 3;
  const int tok0 = blockIdx.x * TPB;

  const int stok  = tid >> 4;
  const int sdseg = tid & 15;
  const int skh   = sdseg >> 3;
  const int sdsub = (sdseg & 7) * 4;
  const float* sgbase = u + (size_t)(tok0 + stok) * DM + skh * 1024 + sdsub;
  float* swp = smem + stok * FB_LSTR + sdseg * 4;

  const int eq  = tid & 511;
  const int ekh = tid >> 9;
  const float* egbase = E + (size_t)ekh * 1024 * NE + eq * 4;
  float* ewp = smem + FB_EOFF + ekh * (FB_DC * NE) + eq * 4;

  float acc[8];
#pragma unroll
  for (int j = 0; j < 8; ++j) acc[j] = 0.f;

  float4 pf[3];
  pf[0] = *(const float4*)(sgbase + 0 * FB_DC);
  pf[1] = *(const float4*)(sgbase + 1 * FB_DC);
  pf[2] = *(const float4*)(sgbase + 2 * FB_DC);
  float4 epf = *(const float4*)(egbase + 0 * (FB_DC * NE));
  *(float4*)(swp + 0) = pf[0];
  *(float4*)(ewp + 0) = epf;
  epf = *(const float4*)(egbase + 1 * (FB_DC * NE));
  __syncthreads();

  for (int c = 0; c < FB_NCH; ++c) {
    if (c + 1 < FB_NCH) {
      *(float4*)(swp + ((c + 1) & 1) * FB_UB) = pf[(c + 1) % 3];
      *(float4*)(ewp + ((c + 1) & 1) * FB_EB) = epf;
    }
    if (c + 2 < FB_NCH)
      epf = *(const float4*)(egbase + (c + 2) * (FB_DC * NE));
    if (c + 3 < FB_NCH)
      pf[c % 3] = *(const float4*)(sgbase + (c + 3) * FB_DC);

    const float* sb = smem + (c & 1) * FB_UB + lane * FB_LSTR + kh * FB_DC;
    const float* eb = smem + FB_EOFF + (c & 1) * FB_EB + kh * (FB_DC * NE) + eg * 8;
#pragma unroll
    for (int s = 0; s < 8; ++s) {
      float4 uf = *(const float4*)(sb + s * 4);
#pragma unroll
      for (int dd = 0; dd < 4; ++dd) {
        const float* er = eb + (s * 4 + dd) * NE;
        float4 e0 = *(const float4*)(er);
        float4 e1 = *(const float4*)(er + 4);
        const float uv = (&uf.x)[dd];
        acc[0] = fmaf(e0.x, uv, acc[0]);
        acc[1] = fmaf(e0.y, uv, acc[1]);
        acc[2] = fmaf(e0.z, uv, acc[2]);
        acc[3] = fmaf(e0.w, uv, acc[3]);
        acc[4] = fmaf(e1.x, uv, acc[4]);
        acc[5] = fmaf(e1.y, uv, acc[5]);
        acc[6] = fmaf(e1.z, uv, acc[6]);
        acc[7] = fmaf(e1.w, uv, acc[7]);
      }
    }
    __syncthreads();
  }

  float* fin = smem;
  if (kh == 0) {
#pragma unroll
    for (int j = 0; j < 8; ++j) fin[lane * 65 + eg * 8 + j] = acc[j];
  }
  __syncthreads();
  if (kh == 1) {
#pragma unroll
    for (int j = 0; j < 8; ++j) fin[lane * 65 + eg * 8 + j] += acc[j];
  }
  __syncthreads();

  const float be = bias[lane];
  float asum = 0.f;
#pragma unroll
  for (int tt = 0; tt < 4; ++tt) {
    const int t = wid * 4 + tt;
    float x = fin[t * 65 + lane] + be;

    float m = x;
#pragma unroll
    for (int off = 32; off > 0; off >>= 1) m = fmaxf(m, __shfl_xor(m, off));
    float p = expf(x - m);
    float s = p;
#pragma unroll
    for (int off = 32; off > 0; off >>= 1) s += __shfl_xor(s, off);
    float sc = p / s;

    out[OFF_SC + (size_t)(tok0 + t) * NE + lane] = sc;
    asum += sc;

    float v = sc;
#pragma unroll
    for (int k = 0; k < TOPK; ++k) {
      float bv = v;
      int   bi = lane;
#pragma unroll
      for (int off = 32; off > 0; off >>= 1) {
        float ov = __shfl_xor(bv, off);
        int   oi = __shfl_xor(bi, off);
        if (ov > bv || (ov == bv && oi < bi)) { bv = ov; bi = oi; }
      }
      if (lane == k) {
        out[OFF_TI + (size_t)(tok0 + t) * TOPK + k] = (float)bi;
        out[OFF_TS + (size_t)(tok0 + t) * TOPK + k] = bv;
      }
      if (lane == bi) v = -INFINITY;
    }
  }
  atomicAdd(&ws[lane], asum);
}

__global__ void router_aux(const float* __restrict__ ws, float* __restrict__ out)
{
  const int lane = threadIdx.x & 63;
  float m = ws[lane] * (1.0f / N_TOK);
  float v = m * m;
#pragma unroll
  for (int off = 32; off > 0; off >>= 1) v += __shfl_xor(v, off);
  if (lane == 0) out[OFF_AUX] = v * (float)NE;
}

extern "C" void kernel_launch(void* const* d_in, const int* in_sizes, int n_in,
                              void* d_out, int out_size, void* d_ws, size_t ws_size,
                              hipStream_t stream) {
  const float* u    = (const float*)d_in[0];
  const float* E    = (const float*)d_in[1];
  const float* bias = (const float*)d_in[2];
  float* out = (float*)d_out;
  float* ws  = (float*)d_ws;

  if (ws_size >= WS_NEED) {
    unsigned short* eh = (unsigned short*)((char*)ws + EH_OFF);
    unsigned short* el = eh + ET_ELEMS;
    router_prep<<<DM / 32, 256, 0, stream>>>(E, eh, el, ws);
    router_main_mfma<<<N_TOK / MTPB, 256, 0, stream>>>(u, eh, el, bias, out, ws);
  } else {
    hipMemsetAsync(ws, 0, NE * sizeof(float), stream);
    router_main_fb<<<N_TOK / TPB, 1024, 0, stream>>>(u, E, bias, out, ws);
    router_aux<<<1, 64, 0, stream>>>(ws, out);
  }
}